// Round 2
// baseline (2897.367 us; speedup 1.0000x reference)
//
#include <hip/hip_runtime.h>

namespace {
constexpr int   NGRID  = 512;
constexpr int   NCELL  = NGRID * NGRID;
constexpr float DX     = 1.0f / (float)NGRID;
constexpr float INV_DX = (float)NGRID;
constexpr float DT     = 1e-4f;
constexpr float P_VOL  = (DX * 0.5f) * (DX * 0.5f);
constexpr float P_MASS = P_VOL * 1.0f;   // p_rho = 1
constexpr float GRAV   = 10.0f;
constexpr int   NXCD   = 8;
}

__device__ __forceinline__ int xcc_id() {
    int x;
    asm volatile("s_getreg_b32 %0, hwreg(HW_REG_XCC_ID)" : "=s"(x));
    return x & 7;
}

// ---------------- P2G: particle -> grid scatter + F/material/Jp outputs ----
// MULTI=true: per-XCD grid copies + workgroup-scope atomics (stay in XCD L2).
// MULTI=false: single copy + device-scope atomics (correct but slow fallback).
template<bool MULTI>
__global__ __launch_bounds__(256) void mpm_p2g(
    const float2* __restrict__ x,
    const float2* __restrict__ v,
    const float4* __restrict__ C,
    const float4* __restrict__ F,
    const int*    __restrict__ material,
    const float*  __restrict__ Jp,
    const float*  __restrict__ Ep,
    const float*  __restrict__ nup,
    float* __restrict__ gbase,      // NCOPY x NCELL x 3 floats (vx,vy,m)
    float4* __restrict__ outF,
    float*  __restrict__ outMat,
    float*  __restrict__ outJp,
    int n)
{
    int p = blockIdx.x * blockDim.x + threadIdx.x;
    if (p >= n) return;

    float* __restrict__ g = MULTI ? (gbase + (size_t)xcc_id() * ((size_t)NCELL * 3))
                                  : gbase;

    const float E  = Ep[0];
    const float nu = nup[0];
    const float mu0 = E / (2.0f * (1.0f + nu));
    const float la0 = E * nu / ((1.0f + nu) * (1.0f - 2.0f * nu));

    const float2 xp = x[p];
    const float2 vp = v[p];
    const float4 c4 = C[p];
    const float4 f4 = F[p];
    const float  jp = Jp[p];

    const float xs = xp.x * INV_DX, ys = xp.y * INV_DX;
    const int bi = (int)(xs - 0.5f);
    const int bj = (int)(ys - 0.5f);
    const float fxx = xs - (float)bi;
    const float fxy = ys - (float)bj;

    float wx[3], wy[3];
    { float t0 = 1.5f - fxx, t1 = fxx - 1.0f, t2 = fxx - 0.5f;
      wx[0] = 0.5f * t0 * t0; wx[1] = 0.75f - t1 * t1; wx[2] = 0.5f * t2 * t2; }
    { float t0 = 1.5f - fxy, t1 = fxy - 1.0f, t2 = fxy - 0.5f;
      wy[0] = 0.5f * t0 * t0; wy[1] = 0.75f - t1 * t1; wy[2] = 0.5f * t2 * t2; }

    // F <- F + dt * C @ F
    const float F00 = f4.x + DT * (c4.x * f4.x + c4.y * f4.z);
    const float F01 = f4.y + DT * (c4.x * f4.y + c4.y * f4.w);
    const float F10 = f4.z + DT * (c4.z * f4.x + c4.w * f4.z);
    const float F11 = f4.w + DT * (c4.z * f4.y + c4.w * f4.w);

    const float h  = expf(10.0f * (1.0f - jp));
    const float mu = mu0 * h;
    const float la = la0 * h;

    const float a = F00 + F11;
    const float b = F10 - F01;
    const float r = sqrtf(a * a + b * b);
    const float cth = a / r;
    const float sth = b / r;
    const float J = fabsf(F00 * F11 - F01 * F10);

    const float A00 = F00 - cth, A01 = F01 + sth;
    const float A10 = F10 - sth, A11 = F11 - cth;
    const float PF00 = A00 * F00 + A01 * F01;
    const float PF01 = A00 * F10 + A01 * F11;
    const float PF10 = A10 * F00 + A11 * F01;
    const float PF11 = A10 * F10 + A11 * F11;

    constexpr float SC = -DT * P_VOL * 4.0f * INV_DX * INV_DX;
    const float diag = la * J * (J - 1.0f);
    const float twomu = 2.0f * mu;
    const float S00 = SC * (twomu * PF00 + diag);
    const float S01 = SC * (twomu * PF01);
    const float S10 = SC * (twomu * PF10);
    const float S11 = SC * (twomu * PF11 + diag);

    const float Af00 = S00 + P_MASS * c4.x;
    const float Af01 = S01 + P_MASS * c4.y;
    const float Af10 = S10 + P_MASS * c4.z;
    const float Af11 = S11 + P_MASS * c4.w;

    const float mvx = P_MASS * vp.x;
    const float mvy = P_MASS * vp.y;

    #pragma unroll
    for (int i = 0; i < 3; ++i) {
        #pragma unroll
        for (int j = 0; j < 3; ++j) {
            const float wgt = wx[i] * wy[j];
            const float dpx = ((float)i - fxx) * DX;
            const float dpy = ((float)j - fxy) * DX;
            const float cx = wgt * (mvx + Af00 * dpx + Af01 * dpy);
            const float cy = wgt * (mvy + Af10 * dpx + Af11 * dpy);
            const size_t k3 = (size_t)((bi + i) * NGRID + (bj + j)) * 3;
            if constexpr (MULTI) {
                __hip_atomic_fetch_add(&g[k3 + 0], cx, __ATOMIC_RELAXED, __HIP_MEMORY_SCOPE_WORKGROUP);
                __hip_atomic_fetch_add(&g[k3 + 1], cy, __ATOMIC_RELAXED, __HIP_MEMORY_SCOPE_WORKGROUP);
                __hip_atomic_fetch_add(&g[k3 + 2], wgt * P_MASS, __ATOMIC_RELAXED, __HIP_MEMORY_SCOPE_WORKGROUP);
            } else {
                atomicAdd(&g[k3 + 0], cx);
                atomicAdd(&g[k3 + 1], cy);
                atomicAdd(&g[k3 + 2], wgt * P_MASS);
            }
        }
    }

    outF[p] = make_float4(F00, F01, F10, F11);
    outMat[p] = (float)material[p];
    outJp[p]  = jp;
}

// ------ reduce 8 copies + momentum->velocity + gravity + BCs --------------
__global__ __launch_bounds__(256) void mpm_reduce_grid(
    const float* __restrict__ copies,   // ncopy x NCELL x 3
    int ncopy,
    float2* __restrict__ gv)            // NCELL x (vx,vy)
{
    int idx = blockIdx.x * blockDim.x + threadIdx.x;
    if (idx >= NCELL) return;
    const int i = idx >> 9;
    const int j = idx & (NGRID - 1);

    float vx = 0.0f, vy = 0.0f, m = 0.0f;
    for (int c = 0; c < ncopy; ++c) {
        const float* p = copies + (size_t)c * ((size_t)NCELL * 3) + (size_t)idx * 3;
        vx += p[0];
        vy += p[1];
        m  += p[2];
    }

    if (m > 0.0f) {
        float inv = 1.0f / fmaxf(m, 1e-30f);
        vx *= inv;
        vy *= inv;
    }
    vy -= DT * GRAV;
    if (i < 3)          vx = fmaxf(vx, 0.0f);
    if (i >= NGRID - 2) vx = fminf(vx, 0.0f);
    if (j < 3)          vy = fmaxf(vy, 0.0f);
    if (j >= NGRID - 2) vy = fminf(vy, 0.0f);
    gv[idx] = make_float2(vx, vy);
}

// ---------------- G2P: grid -> particle gather, x/v/C outputs --------------
__global__ __launch_bounds__(256) void mpm_g2p(
    const float2* __restrict__ x,
    const float2* __restrict__ gv,
    float2* __restrict__ outX,
    float2* __restrict__ outV,
    float4* __restrict__ outC,
    int n)
{
    int p = blockIdx.x * blockDim.x + threadIdx.x;
    if (p >= n) return;

    const float2 xp = x[p];
    const float xs = xp.x * INV_DX, ys = xp.y * INV_DX;
    const int bi = (int)(xs - 0.5f);
    const int bj = (int)(ys - 0.5f);
    const float fxx = xs - (float)bi;
    const float fxy = ys - (float)bj;

    float wx[3], wy[3];
    { float t0 = 1.5f - fxx, t1 = fxx - 1.0f, t2 = fxx - 0.5f;
      wx[0] = 0.5f * t0 * t0; wx[1] = 0.75f - t1 * t1; wx[2] = 0.5f * t2 * t2; }
    { float t0 = 1.5f - fxy, t1 = fxy - 1.0f, t2 = fxy - 0.5f;
      wy[0] = 0.5f * t0 * t0; wy[1] = 0.75f - t1 * t1; wy[2] = 0.5f * t2 * t2; }

    float nvx = 0.0f, nvy = 0.0f;
    float C00 = 0.0f, C01 = 0.0f, C10 = 0.0f, C11 = 0.0f;
    constexpr float K4 = 4.0f * INV_DX * INV_DX;

    #pragma unroll
    for (int i = 0; i < 3; ++i) {
        const float dpx = ((float)i - fxx) * DX;
        const int rowbase = (bi + i) * NGRID + bj;
        #pragma unroll
        for (int j = 0; j < 3; ++j) {
            const float wgt = wx[i] * wy[j];
            const float dpy = ((float)j - fxy) * DX;
            const float2 gvc = gv[rowbase + j];
            nvx += wgt * gvc.x;
            nvy += wgt * gvc.y;
            const float kw = K4 * wgt;
            C00 += kw * gvc.x * dpx;
            C01 += kw * gvc.x * dpy;
            C10 += kw * gvc.y * dpx;
            C11 += kw * gvc.y * dpy;
        }
    }

    outX[p] = make_float2(xp.x + DT * nvx, xp.y + DT * nvy);
    outV[p] = make_float2(nvx, nvy);
    outC[p] = make_float4(C00, C01, C10, C11);
}

extern "C" void kernel_launch(void* const* d_in, const int* in_sizes, int n_in,
                              void* d_out, int out_size, void* d_ws, size_t ws_size,
                              hipStream_t stream) {
    const int n = in_sizes[0] / 2;   // N_PART

    const float2* x   = (const float2*)d_in[0];
    const float2* v   = (const float2*)d_in[1];
    const float4* C   = (const float4*)d_in[2];
    const float4* F   = (const float4*)d_in[3];
    const int*    mat = (const int*)d_in[4];
    const float*  Jp  = (const float*)d_in[5];
    const float*  Ep  = (const float*)d_in[6];
    const float*  nup = (const float*)d_in[7];

    float* out = (float*)d_out;
    float2* o_x = (float2*)(out);
    float2* o_v = (float2*)(out + 2 * (size_t)n);
    float4* o_C = (float4*)(out + 4 * (size_t)n);
    float4* o_F = (float4*)(out + 8 * (size_t)n);
    float*  o_m = out + 12 * (size_t)n;
    float*  o_J = out + 13 * (size_t)n;

    // workspace layout: [ncopy x NCELL x 3] grid copies | [NCELL x float2] final grid
    const size_t copy_floats  = (size_t)NCELL * 3;
    const size_t need_multi   = (copy_floats * NXCD + (size_t)NCELL * 2) * sizeof(float);
    const bool multi = ws_size >= need_multi;
    const int ncopy = multi ? NXCD : 1;

    float*  gcopies = (float*)d_ws;
    float2* gfinal  = (float2*)(gcopies + copy_floats * (size_t)ncopy);

    hipMemsetAsync(d_ws, 0, copy_floats * (size_t)ncopy * sizeof(float), stream);

    const int BLK = 256;
    const int pgrid = (n + BLK - 1) / BLK;

    if (multi) {
        mpm_p2g<true><<<pgrid, BLK, 0, stream>>>(x, v, C, F, mat, Jp, Ep, nup,
                                                 gcopies, o_F, o_m, o_J, n);
    } else {
        mpm_p2g<false><<<pgrid, BLK, 0, stream>>>(x, v, C, F, mat, Jp, Ep, nup,
                                                  gcopies, o_F, o_m, o_J, n);
    }
    mpm_reduce_grid<<<(NCELL + BLK - 1) / BLK, BLK, 0, stream>>>(gcopies, ncopy, gfinal);
    mpm_g2p<<<pgrid, BLK, 0, stream>>>(x, gfinal, o_x, o_v, o_C, n);
}

// Round 3
// 774.172 us; speedup vs baseline: 3.7425x; 3.7425x over previous
//
#include <hip/hip_runtime.h>

namespace {
constexpr int   NGRID  = 512;
constexpr int   NCELL  = NGRID * NGRID;
constexpr float DX     = 1.0f / (float)NGRID;
constexpr float INV_DX = (float)NGRID;
constexpr float DT     = 1e-4f;
constexpr float P_VOL  = (DX * 0.5f) * (DX * 0.5f);
constexpr float P_MASS = P_VOL * 1.0f;   // p_rho = 1
constexpr float GRAV   = 10.0f;

constexpr int TILE  = 16;            // cells per tile side
constexpr int TPR   = NGRID / TILE;  // 32 tiles per row
constexpr int NTILE = TPR * TPR;     // 1024
constexpr int REG   = TILE + 3;      // 19: region rows r0-1 .. r0+17
constexpr int RCELL = REG * REG;     // 361
constexpr int NBLK  = 512;           // blocks for count/scatter
constexpr int BLK   = 256;
}

// ---------------------------------------------------------------- count ----
__global__ __launch_bounds__(256) void k_count(
    const float2* __restrict__ x, int n, int ppb,
    int* __restrict__ cnt /* [NBLK][NTILE] */)
{
    __shared__ int hist[NTILE];
    for (int t = threadIdx.x; t < NTILE; t += BLK) hist[t] = 0;
    __syncthreads();
    const int b0 = blockIdx.x * ppb;
    const int b1 = min(b0 + ppb, n);
    for (int p = b0 + threadIdx.x; p < b1; p += BLK) {
        const float2 xp = x[p];
        const int ci = (int)(xp.x * INV_DX);
        const int cj = (int)(xp.y * INV_DX);
        atomicAdd(&hist[(ci >> 4) * TPR + (cj >> 4)], 1);
    }
    __syncthreads();
    int* row = cnt + (size_t)blockIdx.x * NTILE;
    for (int t = threadIdx.x; t < NTILE; t += BLK) row[t] = hist[t];
}

// ----------------------------------------------------------------- scan ----
// one block, 1024 threads; thread t owns tile t
__global__ __launch_bounds__(1024) void k_scan(
    int* __restrict__ cnt, int* __restrict__ tile_start, int* __restrict__ tile_end)
{
    const int t = threadIdx.x;
    // total per tile (independent loads -> pipelined)
    int s = 0;
    #pragma unroll 8
    for (int b = 0; b < NBLK; ++b) s += cnt[(size_t)b * NTILE + t];

    // exclusive scan of s across 1024 threads
    __shared__ int wsum[16];
    const int lane = t & 63, w = t >> 6;
    int inc = s;
    #pragma unroll
    for (int d = 1; d < 64; d <<= 1) {
        int u = __shfl_up(inc, d, 64);
        if (lane >= d) inc += u;
    }
    if (lane == 63) wsum[w] = inc;
    __syncthreads();
    if (t == 0) {
        int r = 0;
        #pragma unroll
        for (int i = 0; i < 16; ++i) { int v = wsum[i]; wsum[i] = r; r += v; }
    }
    __syncthreads();
    const int base = wsum[w] + inc - s;      // global exclusive prefix for tile t
    tile_start[t] = base;
    tile_end[t]   = base + s;

    // rewrite cnt[b][t] -> global dest start for (b, t)
    int run = base;
    #pragma unroll 8
    for (int b = 0; b < NBLK; ++b) {
        int v = cnt[(size_t)b * NTILE + t];
        cnt[(size_t)b * NTILE + t] = run;
        run += v;
    }
}

// -------------------------------------------------------------- scatter ----
// full per-particle math; packed record = {x.x, x.y, mvx, mvy | Af00..Af11}
__global__ __launch_bounds__(256) void k_scatter(
    const float2* __restrict__ x,
    const float2* __restrict__ v,
    const float4* __restrict__ C,
    const float4* __restrict__ F,
    const int*    __restrict__ material,
    const float*  __restrict__ Jp,
    const float*  __restrict__ Ep,
    const float*  __restrict__ nup,
    int n, int ppb,
    const int* __restrict__ cnt,
    float4* __restrict__ packed,
    float4* __restrict__ outF,
    float*  __restrict__ outMat,
    float*  __restrict__ outJp)
{
    __shared__ int cur[NTILE];
    {
        const int* row = cnt + (size_t)blockIdx.x * NTILE;
        for (int t = threadIdx.x; t < NTILE; t += BLK) cur[t] = row[t];
    }
    __syncthreads();

    const float E  = Ep[0];
    const float nu = nup[0];
    const float mu0 = E / (2.0f * (1.0f + nu));
    const float la0 = E * nu / ((1.0f + nu) * (1.0f - 2.0f * nu));

    const int b0 = blockIdx.x * ppb;
    const int b1 = min(b0 + ppb, n);
    for (int p = b0 + threadIdx.x; p < b1; p += BLK) {
        const float2 xp = x[p];
        const float2 vp = v[p];
        const float4 c4 = C[p];
        const float4 f4 = F[p];
        const float  jp = Jp[p];

        // F <- F + dt * C @ F
        const float F00 = f4.x + DT * (c4.x * f4.x + c4.y * f4.z);
        const float F01 = f4.y + DT * (c4.x * f4.y + c4.y * f4.w);
        const float F10 = f4.z + DT * (c4.z * f4.x + c4.w * f4.z);
        const float F11 = f4.w + DT * (c4.z * f4.y + c4.w * f4.w);

        const float h  = expf(10.0f * (1.0f - jp));
        const float mu = mu0 * h;
        const float la = la0 * h;

        const float a = F00 + F11;
        const float b = F10 - F01;
        const float r = sqrtf(a * a + b * b);
        const float cth = a / r;
        const float sth = b / r;
        const float J = fabsf(F00 * F11 - F01 * F10);

        const float A00 = F00 - cth, A01 = F01 + sth;
        const float A10 = F10 - sth, A11 = F11 - cth;
        const float PF00 = A00 * F00 + A01 * F01;
        const float PF01 = A00 * F10 + A01 * F11;
        const float PF10 = A10 * F00 + A11 * F01;
        const float PF11 = A10 * F10 + A11 * F11;

        constexpr float SC = -DT * P_VOL * 4.0f * INV_DX * INV_DX;
        const float diag = la * J * (J - 1.0f);
        const float twomu = 2.0f * mu;
        const float Af00 = SC * (twomu * PF00 + diag) + P_MASS * c4.x;
        const float Af01 = SC * (twomu * PF01)        + P_MASS * c4.y;
        const float Af10 = SC * (twomu * PF10)        + P_MASS * c4.z;
        const float Af11 = SC * (twomu * PF11 + diag) + P_MASS * c4.w;

        const int ci = (int)(xp.x * INV_DX);
        const int cj = (int)(xp.y * INV_DX);
        const int t  = (ci >> 4) * TPR + (cj >> 4);
        const int slot = atomicAdd(&cur[t], 1);

        packed[2 * (size_t)slot]     = make_float4(xp.x, xp.y, P_MASS * vp.x, P_MASS * vp.y);
        packed[2 * (size_t)slot + 1] = make_float4(Af00, Af01, Af10, Af11);

        outF[p]   = make_float4(F00, F01, F10, F11);
        outMat[p] = (float)material[p];
        outJp[p]  = jp;
    }
}

// ------------------------------------------------------------- p2g tile ----
__global__ __launch_bounds__(256) void k_p2g_tile(
    const float4* __restrict__ packed,
    const int* __restrict__ tile_start,
    const int* __restrict__ tile_end,
    float* __restrict__ gvx, float* __restrict__ gvy, float* __restrict__ gm)
{
    const int t  = blockIdx.x;
    const int s0 = tile_start[t];
    const int s1 = tile_end[t];
    if (s0 == s1) return;                       // uniform: safe before barriers

    __shared__ float acc[RCELL * 3];
    for (int i = threadIdx.x; i < RCELL * 3; i += BLK) acc[i] = 0.0f;
    __syncthreads();

    const int tr = t >> 5, tc = t & 31;         // TPR = 32
    const int r0 = tr * TILE - 1, c0 = tc * TILE - 1;

    for (int p = s0 + threadIdx.x; p < s1; p += BLK) {
        const float4 pa = packed[2 * (size_t)p];
        const float4 pb = packed[2 * (size_t)p + 1];
        const float xs = pa.x * INV_DX, ys = pa.y * INV_DX;
        const int bi = (int)(xs - 0.5f);
        const int bj = (int)(ys - 0.5f);
        const float fxx = xs - (float)bi;
        const float fxy = ys - (float)bj;

        float wx[3], wy[3];
        { float t0 = 1.5f - fxx, t1 = fxx - 1.0f, t2 = fxx - 0.5f;
          wx[0] = 0.5f * t0 * t0; wx[1] = 0.75f - t1 * t1; wx[2] = 0.5f * t2 * t2; }
        { float t0 = 1.5f - fxy, t1 = fxy - 1.0f, t2 = fxy - 0.5f;
          wy[0] = 0.5f * t0 * t0; wy[1] = 0.75f - t1 * t1; wy[2] = 0.5f * t2 * t2; }

        const int li = bi - r0;                 // 0..16
        const int lj = bj - c0;

        #pragma unroll
        for (int i = 0; i < 3; ++i) {
            const float dpx = ((float)i - fxx) * DX;
            #pragma unroll
            for (int j = 0; j < 3; ++j) {
                const float wgt = wx[i] * wy[j];
                const float dpy = ((float)j - fxy) * DX;
                const float cx = wgt * (pa.z + pb.x * dpx + pb.y * dpy);
                const float cy = wgt * (pa.w + pb.z * dpx + pb.w * dpy);
                const int base3 = ((li + i) * REG + (lj + j)) * 3;
                atomicAdd(&acc[base3 + 0], cx);
                atomicAdd(&acc[base3 + 1], cy);
                atomicAdd(&acc[base3 + 2], wgt * P_MASS);
            }
        }
    }
    __syncthreads();

    // writeout: plain stores for exclusive interior, atomics for halo ring
    for (int idx = threadIdx.x; idx < RCELL; idx += BLK) {
        const int lr = idx / REG, lc = idx % REG;
        const int gr = r0 + lr, gc = c0 + lc;
        if ((unsigned)gr >= (unsigned)NGRID || (unsigned)gc >= (unsigned)NGRID) continue;
        const int g = gr * NGRID + gc;
        const float vx = acc[idx * 3 + 0];
        const float vy = acc[idx * 3 + 1];
        const float m  = acc[idx * 3 + 2];
        const bool interior = (lr >= 3 && lr <= 15 && lc >= 3 && lc <= 15);
        if (interior) {
            gvx[g] = vx; gvy[g] = vy; gm[g] = m;
        } else {
            if (vx != 0.0f) atomicAdd(&gvx[g], vx);
            if (vy != 0.0f) atomicAdd(&gvy[g], vy);
            if (m  != 0.0f) atomicAdd(&gm[g],  m);
        }
    }
}

// ----------------------------------------------------------- grid update ----
__global__ __launch_bounds__(256) void k_grid(
    const float* __restrict__ gvx, const float* __restrict__ gvy,
    const float* __restrict__ gm, float2* __restrict__ gv)
{
    const int idx = blockIdx.x * blockDim.x + threadIdx.x;
    if (idx >= NCELL) return;
    const int i = idx >> 9;
    const int j = idx & (NGRID - 1);
    float m = gm[idx], vx = gvx[idx], vy = gvy[idx];
    if (m > 0.0f) {
        const float inv = 1.0f / fmaxf(m, 1e-30f);
        vx *= inv; vy *= inv;
    }
    vy -= DT * GRAV;
    if (i < 3)          vx = fmaxf(vx, 0.0f);
    if (i >= NGRID - 2) vx = fminf(vx, 0.0f);
    if (j < 3)          vy = fmaxf(vy, 0.0f);
    if (j >= NGRID - 2) vy = fminf(vy, 0.0f);
    gv[idx] = make_float2(vx, vy);
}

// ------------------------------------------------------------------ g2p ----
__global__ __launch_bounds__(256) void k_g2p(
    const float2* __restrict__ x,
    const float2* __restrict__ gv,
    float2* __restrict__ outX,
    float2* __restrict__ outV,
    float4* __restrict__ outC,
    int n)
{
    const int p = blockIdx.x * blockDim.x + threadIdx.x;
    if (p >= n) return;

    const float2 xp = x[p];
    const float xs = xp.x * INV_DX, ys = xp.y * INV_DX;
    const int bi = (int)(xs - 0.5f);
    const int bj = (int)(ys - 0.5f);
    const float fxx = xs - (float)bi;
    const float fxy = ys - (float)bj;

    float wx[3], wy[3];
    { float t0 = 1.5f - fxx, t1 = fxx - 1.0f, t2 = fxx - 0.5f;
      wx[0] = 0.5f * t0 * t0; wx[1] = 0.75f - t1 * t1; wx[2] = 0.5f * t2 * t2; }
    { float t0 = 1.5f - fxy, t1 = fxy - 1.0f, t2 = fxy - 0.5f;
      wy[0] = 0.5f * t0 * t0; wy[1] = 0.75f - t1 * t1; wy[2] = 0.5f * t2 * t2; }

    float nvx = 0.0f, nvy = 0.0f;
    float C00 = 0.0f, C01 = 0.0f, C10 = 0.0f, C11 = 0.0f;
    constexpr float K4 = 4.0f * INV_DX * INV_DX;

    #pragma unroll
    for (int i = 0; i < 3; ++i) {
        const float dpx = ((float)i - fxx) * DX;
        const int rowbase = (bi + i) * NGRID + bj;
        #pragma unroll
        for (int j = 0; j < 3; ++j) {
            const float wgt = wx[i] * wy[j];
            const float dpy = ((float)j - fxy) * DX;
            const float2 g = gv[rowbase + j];
            nvx += wgt * g.x;
            nvy += wgt * g.y;
            const float kw = K4 * wgt;
            C00 += kw * g.x * dpx;
            C01 += kw * g.x * dpy;
            C10 += kw * g.y * dpx;
            C11 += kw * g.y * dpy;
        }
    }

    outX[p] = make_float2(xp.x + DT * nvx, xp.y + DT * nvy);
    outV[p] = make_float2(nvx, nvy);
    outC[p] = make_float4(C00, C01, C10, C11);
}

// ------------------------------------------- fallback (small ws): atomics ----
__global__ __launch_bounds__(256) void fb_p2g(
    const float2* __restrict__ x, const float2* __restrict__ v,
    const float4* __restrict__ C, const float4* __restrict__ F,
    const int* __restrict__ material, const float* __restrict__ Jp,
    const float* __restrict__ Ep, const float* __restrict__ nup,
    float* __restrict__ g,           // NCELL x 3 interleaved
    float4* __restrict__ outF, float* __restrict__ outMat, float* __restrict__ outJp,
    int n)
{
    const int p = blockIdx.x * blockDim.x + threadIdx.x;
    if (p >= n) return;
    const float E = Ep[0], nu = nup[0];
    const float mu0 = E / (2.0f * (1.0f + nu));
    const float la0 = E * nu / ((1.0f + nu) * (1.0f - 2.0f * nu));
    const float2 xp = x[p]; const float2 vp = v[p];
    const float4 c4 = C[p]; const float4 f4 = F[p];
    const float jp = Jp[p];
    const float xs = xp.x * INV_DX, ys = xp.y * INV_DX;
    const int bi = (int)(xs - 0.5f), bj = (int)(ys - 0.5f);
    const float fxx = xs - (float)bi, fxy = ys - (float)bj;
    float wx[3], wy[3];
    { float t0 = 1.5f - fxx, t1 = fxx - 1.0f, t2 = fxx - 0.5f;
      wx[0] = 0.5f * t0 * t0; wx[1] = 0.75f - t1 * t1; wx[2] = 0.5f * t2 * t2; }
    { float t0 = 1.5f - fxy, t1 = fxy - 1.0f, t2 = fxy - 0.5f;
      wy[0] = 0.5f * t0 * t0; wy[1] = 0.75f - t1 * t1; wy[2] = 0.5f * t2 * t2; }
    const float F00 = f4.x + DT * (c4.x * f4.x + c4.y * f4.z);
    const float F01 = f4.y + DT * (c4.x * f4.y + c4.y * f4.w);
    const float F10 = f4.z + DT * (c4.z * f4.x + c4.w * f4.z);
    const float F11 = f4.w + DT * (c4.z * f4.y + c4.w * f4.w);
    const float h = expf(10.0f * (1.0f - jp));
    const float mu = mu0 * h, la = la0 * h;
    const float a = F00 + F11, b = F10 - F01;
    const float r = sqrtf(a * a + b * b);
    const float cth = a / r, sth = b / r;
    const float J = fabsf(F00 * F11 - F01 * F10);
    const float A00 = F00 - cth, A01 = F01 + sth;
    const float A10 = F10 - sth, A11 = F11 - cth;
    constexpr float SC = -DT * P_VOL * 4.0f * INV_DX * INV_DX;
    const float diag = la * J * (J - 1.0f);
    const float twomu = 2.0f * mu;
    const float Af00 = SC * (twomu * (A00 * F00 + A01 * F01) + diag) + P_MASS * c4.x;
    const float Af01 = SC * (twomu * (A00 * F10 + A01 * F11))        + P_MASS * c4.y;
    const float Af10 = SC * (twomu * (A10 * F00 + A11 * F01))        + P_MASS * c4.z;
    const float Af11 = SC * (twomu * (A10 * F10 + A11 * F11) + diag) + P_MASS * c4.w;
    const float mvx = P_MASS * vp.x, mvy = P_MASS * vp.y;
    #pragma unroll
    for (int i = 0; i < 3; ++i) {
        #pragma unroll
        for (int j = 0; j < 3; ++j) {
            const float wgt = wx[i] * wy[j];
            const float dpx = ((float)i - fxx) * DX;
            const float dpy = ((float)j - fxy) * DX;
            const size_t k3 = (size_t)((bi + i) * NGRID + (bj + j)) * 3;
            atomicAdd(&g[k3 + 0], wgt * (mvx + Af00 * dpx + Af01 * dpy));
            atomicAdd(&g[k3 + 1], wgt * (mvy + Af10 * dpx + Af11 * dpy));
            atomicAdd(&g[k3 + 2], wgt * P_MASS);
        }
    }
    outF[p] = make_float4(F00, F01, F10, F11);
    outMat[p] = (float)material[p];
    outJp[p] = jp;
}

__global__ __launch_bounds__(256) void fb_grid(
    const float* __restrict__ g, float2* __restrict__ gv)
{
    const int idx = blockIdx.x * blockDim.x + threadIdx.x;
    if (idx >= NCELL) return;
    const int i = idx >> 9, j = idx & (NGRID - 1);
    float vx = g[(size_t)idx * 3], vy = g[(size_t)idx * 3 + 1], m = g[(size_t)idx * 3 + 2];
    if (m > 0.0f) { const float inv = 1.0f / fmaxf(m, 1e-30f); vx *= inv; vy *= inv; }
    vy -= DT * GRAV;
    if (i < 3)          vx = fmaxf(vx, 0.0f);
    if (i >= NGRID - 2) vx = fminf(vx, 0.0f);
    if (j < 3)          vy = fmaxf(vy, 0.0f);
    if (j >= NGRID - 2) vy = fminf(vy, 0.0f);
    gv[idx] = make_float2(vx, vy);
}

extern "C" void kernel_launch(void* const* d_in, const int* in_sizes, int n_in,
                              void* d_out, int out_size, void* d_ws, size_t ws_size,
                              hipStream_t stream) {
    const int n = in_sizes[0] / 2;   // N_PART

    const float2* x   = (const float2*)d_in[0];
    const float2* v   = (const float2*)d_in[1];
    const float4* C   = (const float4*)d_in[2];
    const float4* F   = (const float4*)d_in[3];
    const int*    mat = (const int*)d_in[4];
    const float*  Jp  = (const float*)d_in[5];
    const float*  Ep  = (const float*)d_in[6];
    const float*  nup = (const float*)d_in[7];

    float* out = (float*)d_out;
    float2* o_x = (float2*)(out);
    float2* o_v = (float2*)(out + 2 * (size_t)n);
    float4* o_C = (float4*)(out + 4 * (size_t)n);
    float4* o_F = (float4*)(out + 8 * (size_t)n);
    float*  o_m = out + 12 * (size_t)n;
    float*  o_J = out + 13 * (size_t)n;

    const int BLOCK = 256;
    const int pgrid = (n + BLOCK - 1) / BLOCK;
    const int ggrid = (NCELL + BLOCK - 1) / BLOCK;

    // fast-path workspace layout
    char* w = (char*)d_ws;
    float4* packed = (float4*)w;            w += (size_t)n * 2 * sizeof(float4);
    int* cnt    = (int*)w;                  w += (size_t)NBLK * NTILE * sizeof(int);
    int* tstart = (int*)w;                  w += (size_t)NTILE * sizeof(int);
    int* tend   = (int*)w;                  w += (size_t)NTILE * sizeof(int);
    float* gvx  = (float*)w;                w += (size_t)NCELL * sizeof(float);
    float* gvy  = (float*)w;                w += (size_t)NCELL * sizeof(float);
    float* gm   = (float*)w;                w += (size_t)NCELL * sizeof(float);
    float2* gfin= (float2*)w;               w += (size_t)NCELL * sizeof(float2);
    const size_t need = (size_t)(w - (char*)d_ws);

    if (ws_size >= need) {
        const int ppb = (n + NBLK - 1) / NBLK;
        hipMemsetAsync(gvx, 0, (size_t)NCELL * 3 * sizeof(float), stream);
        k_count  <<<NBLK, BLOCK, 0, stream>>>(x, n, ppb, cnt);
        k_scan   <<<1, 1024, 0, stream>>>(cnt, tstart, tend);
        k_scatter<<<NBLK, BLOCK, 0, stream>>>(x, v, C, F, mat, Jp, Ep, nup,
                                              n, ppb, cnt, packed, o_F, o_m, o_J);
        k_p2g_tile<<<NTILE, BLOCK, 0, stream>>>(packed, tstart, tend, gvx, gvy, gm);
        k_grid   <<<ggrid, BLOCK, 0, stream>>>(gvx, gvy, gm, gfin);
        k_g2p    <<<pgrid, BLOCK, 0, stream>>>(x, gfin, o_x, o_v, o_C, n);
    } else {
        // fallback: single grid copy + device atomics
        float* g = (float*)d_ws;                       // NCELL*3
        float2* gf = (float2*)(g + (size_t)NCELL * 3); // NCELL float2
        hipMemsetAsync(g, 0, (size_t)NCELL * 3 * sizeof(float), stream);
        fb_p2g <<<pgrid, BLOCK, 0, stream>>>(x, v, C, F, mat, Jp, Ep, nup,
                                             g, o_F, o_m, o_J, n);
        fb_grid<<<ggrid, BLOCK, 0, stream>>>(g, gf);
        k_g2p  <<<pgrid, BLOCK, 0, stream>>>(x, gf, o_x, o_v, o_C, n);
    }
}